// Round 7
// baseline (2052.850 us; speedup 1.0000x reference)
//
#include <hip/hip_runtime.h>

typedef __bf16 bf16x8 __attribute__((ext_vector_type(8)));
typedef float  f32x4  __attribute__((ext_vector_type(4)));

union U4 { uint4 u; bf16x8 v; };

__device__ __forceinline__ bf16x8 ld_frag(const void* p) {
    U4 t; t.u = *(const uint4*)p; return t.v;
}
__device__ __forceinline__ bf16x8 zfrag() {
    bf16x8 z;
#pragma unroll
    for (int jj = 0; jj < 8; jj++) z[jj] = (__bf16)0.f;
    return z;
}

// ---------------------------------------------------------------------------
// R19 h-I/O, templated on the coherence point for DATA only:
//   L2C=false: sc0 sc1  -> bypass L1+L2, L3/MALL coherence point (R12-exact).
//   L2C=true : sc0      -> bypass L1 only; XCD-local L2 is the coherence
//              point. Legal only when the group's 8 blocks share one L2 --
//              established at runtime by a hardware coherence PROBE (below),
//              not by XCC_ID (R13/R14 lesson: that check can pass vacuously).
// FLAGS ALWAYS use agent-scope atomics at L3 in both modes -> the sync
// protocol is placement-independent and cannot deadlock.
// ---------------------------------------------------------------------------
template<bool L2C> __device__ __forceinline__ void ld16_c(const void* p, uint4* d) {
    if (L2C) asm volatile("global_load_dwordx4 %0, %1, off sc0" : "=v"(*d) : "v"(p));
    else     asm volatile("global_load_dwordx4 %0, %1, off sc0 sc1" : "=v"(*d) : "v"(p));
}
template<bool L2C> __device__ __forceinline__ void ld4_c(const void* p, unsigned* d) {
    if (L2C) asm volatile("global_load_dword %0, %1, off sc0" : "=v"(*d) : "v"(p));
    else     asm volatile("global_load_dword %0, %1, off sc0 sc1" : "=v"(*d) : "v"(p));
}
template<bool L2C> __device__ __forceinline__ void st4_c(void* p, unsigned v) {
    if (L2C) asm volatile("global_store_dword %0, %1, off sc0" :: "v"(p), "v"(v) : "memory");
    else     asm volatile("global_store_dword %0, %1, off sc0 sc1" :: "v"(p), "v"(v) : "memory");
}
__device__ __forceinline__ void wait_vm0() {
    asm volatile("s_waitcnt vmcnt(0)" ::: "memory");
}
// scalar-component register pin (R11 compile fix)
#define PIN32(x) asm volatile("" : "+v"(x))
__device__ __forceinline__ void pin_u4(uint4& u) {
    PIN32(u.x); PIN32(u.y); PIN32(u.z); PIN32(u.w);
}

__device__ __forceinline__ unsigned ald_u32(const void* p) {
    return __hip_atomic_load((const unsigned*)p, __ATOMIC_RELAXED, __HIP_MEMORY_SCOPE_AGENT);
}
__device__ __forceinline__ unsigned bf16_bits(float f) {
    __bf16 h = (__bf16)f; unsigned short s;
    __builtin_memcpy(&s, &h, 2); return (unsigned)s;
}
__device__ __forceinline__ float bf16_lo(unsigned v) {
    unsigned u = (v & 0xffffu) << 16; float f;
    __builtin_memcpy(&f, &u, 4); return f;
}
__device__ __forceinline__ float bf16_hi(unsigned v) {
    unsigned u = v & 0xffff0000u; float f;
    __builtin_memcpy(&f, &u, 4); return f;
}

__device__ __forceinline__ void gl_lds16(const uint4* g, void* l) {
    __builtin_amdgcn_global_load_lds(
        (const __attribute__((address_space(1))) unsigned int*)g,
        (__attribute__((address_space(3))) unsigned int*)l, 16, 0, 0);
}

__device__ __forceinline__ float sigf(float x) {
    return __builtin_amdgcn_rcpf(1.f + __expf(-x));
}
__device__ __forceinline__ float tanhf_fast(float x) {
    return 1.f - 2.f * __builtin_amdgcn_rcpf(1.f + __expf(2.f * x));
}

#define MFMA(A,B,C) C = __builtin_amdgcn_mfma_f32_16x16x32_bf16(A, B, C, 0, 0, 0)

// ---------------------------------------------------------------------------
// pack: [Wx(16,pad 32); Uh(256); Uh2(256)] -> B-fragments. (unchanged)
// ---------------------------------------------------------------------------
__global__ void pack_kernel(const float* __restrict__ Wx, const float* __restrict__ Uh,
                            const float* __restrict__ Uh2, uint4* __restrict__ packW) {
    int tid = blockIdx.x * 256 + threadIdx.x;   // 4*17*48*64 = 208896
    int lane = tid & 63;
    int nt   = (tid >> 6) % 48;
    int kt   = ((tid >> 6) / 48) % 17;
    int a    = (tid >> 6) / (48 * 17);
    int col  = nt * 16 + (lane & 15);
    U4 u;
#pragma unroll
    for (int jj = 0; jj < 8; jj++) {
        int p  = (lane >> 4) * 8 + jj;
        int kk = (kt == 0) ? p : (((p & 1) << 4) | (p >> 1));
        int k  = kt * 32 + kk;
        float v;
        if (k < 16)       v = Wx[(a * 16 + k) * 768 + col];
        else if (k < 32)  v = 0.f;
        else if (k < 288) v = Uh[(a * 256 + (k - 32)) * 768 + col];
        else              v = Uh2[(a * 256 + (k - 288)) * 768 + col];
        u.v[jj] = (__bf16)v;
    }
    packW[tid] = u.u;
}

// xpack[a][i29][j29][m256][q2] = 8 bf16 of patch element k=q*8+jj (unchanged)
__global__ void xpack_kernel(const float* __restrict__ x, uint4* __restrict__ xp) {
    int tid = blockIdx.x * 256 + threadIdx.x;   // 1,722,368
    int q = tid & 1;
    int m = (tid >> 1) & 255;
    int rem = tid >> 9;
    int j = rem % 29;
    int t2 = rem / 29;
    int i = t2 % 29;
    int a = t2 / 29;
    int Ny = 29 - (a & 1), Nx = 29 - ((a >> 1) & 1);
    U4 u;
    if (i < Ny && j < Nx) {
        int y0 = (a & 1) ? (27 - i) : i;
        int x0 = (a & 2) ? (27 - j) : j;
        const float* px = x + m * 1024 + y0 * 32 + x0;
#pragma unroll
        for (int jj = 0; jj < 8; jj++) {
            int k = q * 8 + jj;
            u.v[jj] = (__bf16)px[(k >> 2) * 32 + (k & 3)];
        }
    } else {
#pragma unroll
        for (int jj = 0; jj < 8; jj++) u.v[jj] = (__bf16)0.f;
    }
    xp[tid] = u.u;
}

// ---------------------------------------------------------------------------
// Persistent dataflow body: EXACT R12 cell schedule; only the h ld/st carry
// the L2C template. Flags (wait_ge + atomics) are identical in both modes.
// ---------------------------------------------------------------------------
template<bool L2C>
__device__ void persist_body(const float* __restrict__ x, const uint4* __restrict__ xpack,
                             const float* __restrict__ bias, char* __restrict__ hbuf,
                             unsigned* __restrict__ flags, unsigned char* smem,
                             int G, int g)
{
    int a  = G >> 3, s8 = G & 7;
    int Ny = 29 - (a & 1), Nx = 29 - ((a >> 1) & 1);
    char* hbg = hbuf + (size_t)G * 1425408;
    unsigned* prog = flags + G * 32;
    unsigned* cons = flags + 1024 + G * 32;

    int tid  = threadIdx.x;
    int w8   = tid >> 6;
    int lane = tid & 63;
    int q    = lane >> 4;
    int l16  = lane & 15;

    const float* ba = bias + a * 768;
    int c0 = g * 32 + l16;
    float bR0 = ba[c0],      bZ0 = ba[256 + c0],      bN0 = ba[512 + c0];
    float bR1 = ba[c0 + 16], bZ1 = ba[256 + c0 + 16], bN1 = ba[512 + c0 + 16];

    // single-lane poll + wave broadcast (agent atomics at L3, both modes)
    auto wait_ge = [&](unsigned* f, unsigned v) {
        for (;;) {
            unsigned cur = 0;
            if (lane == 0) cur = ald_u32(f);
            cur = __builtin_amdgcn_readfirstlane(cur);
            if ((int)cur >= (int)v) break;
            __builtin_amdgcn_s_sleep(2);
        }
        __asm__ volatile("" ::: "memory");
    };

    // contiguous strip for wave w8
    int sbase = Nx >> 3, srem = Nx & 7;
    int js = w8 * sbase + (w8 < srem ? w8 : srem);
    int je = js + sbase + (w8 < srem ? 1 : 0);

    for (int i = 0; i < Ny; ++i) {
        for (int j = js; j < je; ++j) {
            bool hasA = (i > 0);
            bool hasL = (j > 0);

            bf16x8 afx[2];
            if (xpack) {
                const uint4* xpc = xpack + (size_t)((a * 29 + i) * 29 + j) * 512
                                  + (size_t)(s8 * 32) * 2 + q;
#pragma unroll
                for (int mt = 0; mt < 2; mt++) {
                    if (q < 2) afx[mt] = ld_frag(xpc + (mt * 16 + l16) * 2);
                    else       afx[mt] = zfrag();
                }
            } else {
                int y0 = (a & 1) ? (27 - i) : i;
                int x0 = (a & 2) ? (27 - j) : j;
#pragma unroll
                for (int mt = 0; mt < 2; mt++) {
                    if (q < 2) {
                        int m = s8 * 32 + mt * 16 + l16;
                        const float* xp = x + m * 1024 + (y0 + 2 * q) * 32 + x0;
#pragma unroll
                        for (int jj = 0; jj < 8; jj++)
                            afx[mt][jj] = (__bf16)xp[(jj >> 2) * 32 + (jj & 3)];
                    } else afx[mt] = zfrag();
                }
            }

            // ---- dataflow waits ----
            if (hasA) wait_ge(prog + j, 8u * (unsigned)i);
            if (hasL) wait_ge(prog + j - 1, 8u * (unsigned)(i + 1));

            const char* sA = hbg + (size_t)(j * 3 + ((i - 1) % 3)) * 16384;
            const char* sL = hbg + (size_t)((j - 1) * 3 + (i % 3)) * 16384;

            U4 rA[8][2], rL[8][2];
            unsigned hsA[8], hsL[8];
            if (hasA) {
#pragma unroll
                for (int kt = 0; kt < 8; kt++)
#pragma unroll
                    for (int mt = 0; mt < 2; mt++)
                        ld16_c<L2C>(sA + kt * 2048 + (mt * 16 + l16) * 64 + q * 16,
                                    &rA[kt][mt].u);
#pragma unroll
                for (int mt = 0; mt < 2; mt++)
#pragma unroll
                    for (int e = 0; e < 4; e++)
                        ld4_c<L2C>(sA + g * 2048 + (mt * 16 + q * 4 + e) * 64 + l16 * 4,
                                   &hsA[mt * 4 + e]);
            }
            if (hasL) {
#pragma unroll
                for (int kt = 0; kt < 8; kt++)
#pragma unroll
                    for (int mt = 0; mt < 2; mt++)
                        ld16_c<L2C>(sL + kt * 2048 + (mt * 16 + l16) * 64 + q * 16,
                                    &rL[kt][mt].u);
#pragma unroll
                for (int mt = 0; mt < 2; mt++)
#pragma unroll
                    for (int e = 0; e < 4; e++)
                        ld4_c<L2C>(sL + g * 2048 + (mt * 16 + q * 4 + e) * 64 + l16 * 4,
                                   &hsL[mt * 4 + e]);
            }
            wait_vm0();
            if (hasA) {
#pragma unroll
                for (int kt = 0; kt < 8; kt++)
#pragma unroll
                    for (int mt = 0; mt < 2; mt++) pin_u4(rA[kt][mt].u);
#pragma unroll
                for (int e = 0; e < 8; e++) PIN32(hsA[e]);
            }
            if (hasL) {
#pragma unroll
                for (int kt = 0; kt < 8; kt++)
#pragma unroll
                    for (int mt = 0; mt < 2; mt++) pin_u4(rL[kt][mt].u);
#pragma unroll
                for (int e = 0; e < 8; e++) PIN32(hsL[e]);
            }

            f32x4 acc[2][6];
#pragma unroll
            for (int mt = 0; mt < 2; mt++)
#pragma unroll
                for (int cf = 0; cf < 6; cf++)
#pragma unroll
                    for (int e = 0; e < 4; e++) acc[mt][cf][e] = 0.f;

            // ---- x-stage ----
            f32x4 tn0[2], tn1[2];
            {
                const unsigned char* bb = smem + (size_t)16 * 6144 + lane * 16;
#pragma unroll
                for (int cf = 0; cf < 4; cf++) {
                    bf16x8 bf = ld_frag(bb + cf * 1024);
#pragma unroll
                    for (int mt = 0; mt < 2; mt++) MFMA(afx[mt], bf, acc[mt][cf]);
                }
                bf16x8 bn0 = ld_frag(bb + 4 * 1024);
                bf16x8 bn1 = ld_frag(bb + 5 * 1024);
#pragma unroll
                for (int mt = 0; mt < 2; mt++) {
                    f32x4 z4 = {0.f, 0.f, 0.f, 0.f};
                    tn0[mt] = __builtin_amdgcn_mfma_f32_16x16x32_bf16(afx[mt], bn0, z4, 0, 0, 0);
                    tn1[mt] = __builtin_amdgcn_mfma_f32_16x16x32_bf16(afx[mt], bn1, z4, 0, 0, 0);
                }
            }

            // ---- 16 h-stages ----
            if (hasA) {
#pragma unroll
                for (int s = 0; s < 8; s++) {
                    const unsigned char* bb = smem + (size_t)s * 6144 + lane * 16;
#pragma unroll
                    for (int cf = 0; cf < 6; cf++) {
                        bf16x8 bf = ld_frag(bb + cf * 1024);
#pragma unroll
                        for (int mt = 0; mt < 2; mt++) MFMA(rA[s][mt].v, bf, acc[mt][cf]);
                    }
                }
            }
            if (hasL) {
#pragma unroll
                for (int s = 0; s < 8; s++) {
                    const unsigned char* bb = smem + (size_t)(8 + s) * 6144 + lane * 16;
#pragma unroll
                    for (int cf = 0; cf < 6; cf++) {
                        bf16x8 bf = ld_frag(bb + cf * 1024);
#pragma unroll
                        for (int mt = 0; mt < 2; mt++) MFMA(rL[s][mt].v, bf, acc[mt][cf]);
                    }
                }
            }

            // ---- back-pressure ----
            if (j < Nx - 1 && i >= 3) wait_ge(cons + j, 8u * (unsigned)(i - 2));

            // ---- epilogue ----
            char* sO = hbg + (size_t)(j * 3 + (i % 3)) * 16384;
#pragma unroll
            for (int mt = 0; mt < 2; mt++) {
#pragma unroll
                for (int e = 0; e < 4; e++) {
                    int m = mt * 16 + q * 4 + e;
                    float rv0 = sigf(acc[mt][0][e] + bR0);
                    float zv0 = sigf(acc[mt][2][e] + bZ0);
                    float nv0 = tanhf_fast(tn0[mt][e] + bN0 + rv0 * acc[mt][4][e]);
                    float rv1 = sigf(acc[mt][1][e] + bR1);
                    float zv1 = sigf(acc[mt][3][e] + bZ1);
                    float nv1 = tanhf_fast(tn1[mt][e] + bN1 + rv1 * acc[mt][5][e]);
                    float hs0 = 0.f, hs1 = 0.f;
                    if (hasA) {
                        unsigned v = hsA[mt * 4 + e];
                        hs0 += bf16_lo(v); hs1 += bf16_hi(v);
                    }
                    if (hasL) {
                        unsigned v = hsL[mt * 4 + e];
                        hs0 += bf16_lo(v); hs1 += bf16_hi(v);
                    }
                    float h0 = (1.f - zv0) * nv0 + 0.5f * zv0 * hs0;
                    float h1 = (1.f - zv1) * nv1 + 0.5f * zv1 * hs1;
                    st4_c<L2C>(sO + (size_t)g * 2048 + (size_t)m * 64 + l16 * 4,
                               bf16_bits(h0) | (bf16_bits(h1) << 16));
                }
            }

            wait_vm0();   // stores ack'd at the mode's coherence point
            if (lane == 0) {
                __hip_atomic_fetch_add(prog + j, 1u, __ATOMIC_RELAXED,
                                       __HIP_MEMORY_SCOPE_AGENT);
                if (hasL)
                    __hip_atomic_fetch_add(cons + j - 1, 1u, __ATOMIC_RELAXED,
                                           __HIP_MEMORY_SCOPE_AGENT);
            }
        }
    }
}

// ---------------------------------------------------------------------------
// Kernel: hardware coherence probe per group, then R12 body in sc0 (shared-L2)
// or sc0sc1 (L3) mode. Probe protocol uses ONLY agent atomics for control ->
// cannot hang; a wrong mode decision requires all 32 probe lines to be
// evicted from the writer's L2 within ~us (P~0). Unanimous pass required.
// ---------------------------------------------------------------------------
__global__ __launch_bounds__(512, 2) void persist_kernel(
    const float* __restrict__ x, const uint4* __restrict__ xpack,
    const uint4* __restrict__ packW, const float* __restrict__ bias,
    char* __restrict__ hbuf, unsigned* __restrict__ flags,
    unsigned* __restrict__ probe)
{
    extern __shared__ __align__(16) unsigned char smem[];   // 104448 B

    int bx = blockIdx.x;
    int G  = bx & 31;
    int g  = bx >> 5;
    int a  = G >> 3;
    int tid  = threadIdx.x;
    int w8   = tid >> 6;
    int lane = tid & 63;

    // ---- one-time B preload (async; probe overlaps the fill) ----
    for (int c = w8; c < 102; c += 8) {
        int s  = c / 6;
        int cc = c - s * 6;
        int kt = (s == 16) ? 0 : (s + 1);
        int nt = (cc >> 1) * 16 + 2 * g + (cc & 1);
        gl_lds16(packW + (size_t)(a * 17 + kt) * 3072 + nt * 64 + lane,
                 smem + (size_t)c * 1024);
    }

    // ---- coherence probe (zeroed region; 8 KB per group) ----
    unsigned en = 0;
    if (probe) {
        unsigned* pg   = probe + (size_t)G * 2048;   // 32 lines @128B: pg[l*32]
        unsigned* ctrl = pg + 1024;                  // [0]=wr_done [1]=votes [2]=cnt
        if (tid == 0) {
            if (g == 0) {
                for (int l = 0; l < 32; ++l)
                    st4_c<true>(pg + l * 32, 0xC0DE0000u | (G << 8) | (unsigned)l);
                wait_vm0();
                __hip_atomic_fetch_add(ctrl + 0, 1u, __ATOMIC_RELAXED,
                                       __HIP_MEMORY_SCOPE_AGENT);
            } else {
                while (ald_u32(ctrl + 0) < 1u) __builtin_amdgcn_s_sleep(2);
                unsigned pass = 1u;
                for (int l = 0; l < 32; ++l) {
                    unsigned v;
                    ld4_c<true>(pg + l * 32, &v);
                    wait_vm0(); PIN32(v);
                    if (v != (0xC0DE0000u | (G << 8) | (unsigned)l)) pass = 0u;
                }
                __hip_atomic_fetch_add(ctrl + 1, pass, __ATOMIC_RELAXED,
                                       __HIP_MEMORY_SCOPE_AGENT);
                __hip_atomic_fetch_add(ctrl + 2, 1u, __ATOMIC_RELAXED,
                                       __HIP_MEMORY_SCOPE_AGENT);
            }
        }
        // every wave: poll all-peers-voted, read verdict, wave-broadcast
        for (;;) {
            unsigned c = 0;
            if (lane == 0) c = ald_u32(ctrl + 2);
            c = __builtin_amdgcn_readfirstlane(c);
            if (c >= 7u) break;
            __builtin_amdgcn_s_sleep(2);
        }
        unsigned v = 0;
        if (lane == 0) v = ald_u32(ctrl + 1);
        v = __builtin_amdgcn_readfirstlane(v);
        en = (v == 7u) ? 1u : 0u;
    }

    __syncthreads();   // drains global_load_lds (the only barrier)

    if (en) persist_body<true >(x, xpack, bias, hbuf, flags, smem, G, g);
    else    persist_body<false>(x, xpack, bias, hbuf, flags, smem, G, g);
}

// ---------------------------------------------------------------------------
// Output: logits = hcat @ W_out + b_out, then log_softmax. One wave per batch.
// (Correct in both modes: persist_kernel's end-of-kernel release writes back
// dirty L2 lines -- the same mechanism the baseline relies on for packW.)
// ---------------------------------------------------------------------------
__global__ __launch_bounds__(64) void out_kernel(const char* __restrict__ hbuf,
    const float* __restrict__ Wout, const float* __restrict__ bout,
    float* __restrict__ out)
{
    int b = blockIdx.x;
    int tt = threadIdx.x;
    float accv[10];
#pragma unroll
    for (int o = 0; o < 10; o++) accv[o] = 0.f;
    for (int it = 0; it < 16; ++it) {
        int k = it * 64 + tt;
        int a = k >> 8, c = k & 255;
        int Ny = 29 - (a & 1), Nx = 29 - ((a >> 1) & 1);
        int G  = a * 8 + (b >> 5);
        int c31 = c & 31;
        int pos = ((c31 & 15) << 1) | (c31 >> 4);
        const __bf16* hp = (const __bf16*)(hbuf + (size_t)G * 1425408
                           + (size_t)((Nx - 1) * 3 + (Ny - 1) % 3) * 16384
                           + (size_t)(c >> 5) * 2048 + (size_t)(b & 31) * 64
                           + (size_t)pos * 2);
        float h = (float)(*hp);
        const float* wr = Wout + k * 10;
#pragma unroll
        for (int o = 0; o < 10; o++) accv[o] += h * wr[o];
    }
#pragma unroll
    for (int off = 32; off > 0; off >>= 1)
#pragma unroll
        for (int o = 0; o < 10; o++) accv[o] += __shfl_down(accv[o], off, 64);
    if (tt == 0) {
        float l[10];
#pragma unroll
        for (int o = 0; o < 10; o++) l[o] = accv[o] + bout[o];
        float mx = l[0];
#pragma unroll
        for (int o = 1; o < 10; o++) mx = fmaxf(mx, l[o]);
        float se = 0.f;
#pragma unroll
        for (int o = 0; o < 10; o++) se += __expf(l[o] - mx);
        float lse = mx + __logf(se);
#pragma unroll
        for (int o = 0; o < 10; o++) out[b * 10 + o] = l[o] - lse;
    }
}

extern "C" void kernel_launch(void* const* d_in, const int* in_sizes, int n_in,
                              void* d_out, int out_size, void* d_ws, size_t ws_size,
                              hipStream_t stream) {
    const float* x    = (const float*)d_in[0];
    const float* Wx   = (const float*)d_in[1];
    const float* Uh   = (const float*)d_in[2];
    const float* Uh2  = (const float*)d_in[3];
    const float* b    = (const float*)d_in[4];
    const float* Wout = (const float*)d_in[5];
    const float* bout = (const float*)d_in[6];
    float* out = (float*)d_out;

    char* ws = (char*)d_ws;
    const size_t PACK_PAD    = 3407872;
    const size_t XPACK_END   = 31457280;     // pack + xpack (padded)
    const size_t HBUF_BYTES  = 45613056;     // 32 * 29 * 3 * 16384
    const size_t FLAG_BYTES  = 8192;
    const size_t PROBE_BYTES = 262144;       // 32 groups x 8 KB
    bool use_xp = (ws_size >= XPACK_END + HBUF_BYTES + FLAG_BYTES);

    uint4*  packW = (uint4*)ws;
    uint4*  xpack = use_xp ? (uint4*)(ws + PACK_PAD) : nullptr;
    size_t  hbuf_off = use_xp ? XPACK_END : PACK_PAD;
    char*   hbuf  = ws + hbuf_off;
    unsigned* flags = (unsigned*)(ws + hbuf_off + HBUF_BYTES);
    bool use_probe = (ws_size >= hbuf_off + HBUF_BYTES + FLAG_BYTES + PROBE_BYTES);
    unsigned* probe = use_probe ? flags + 2048 : nullptr;

    (void)hipFuncSetAttribute((const void*)persist_kernel,
                              hipFuncAttributeMaxDynamicSharedMemorySize, 104448);

    hipMemsetAsync(flags, 0, use_probe ? FLAG_BYTES + PROBE_BYTES : FLAG_BYTES, stream);
    pack_kernel<<<816, 256, 0, stream>>>(Wx, Uh, Uh2, packW);
    if (use_xp)
        xpack_kernel<<<6728, 256, 0, stream>>>(x, xpack);

    void* args[] = { (void*)&x, (void*)&xpack, (void*)&packW, (void*)&b,
                     (void*)&hbuf, (void*)&flags, (void*)&probe };
    hipLaunchCooperativeKernel((void*)persist_kernel, dim3(256), dim3(512),
                               args, 104448, stream);

    out_kernel<<<256, 64, 0, stream>>>(hbuf, Wout, bout, out);
}

// Round 9
// 2027.945 us; speedup vs baseline: 1.0123x; 1.0123x over previous
//
#include <hip/hip_runtime.h>

typedef __bf16 bf16x8 __attribute__((ext_vector_type(8)));
typedef float  f32x4  __attribute__((ext_vector_type(4)));

union U4 { uint4 u; bf16x8 v; };

__device__ __forceinline__ bf16x8 ld_frag(const void* p) {
    U4 t; t.u = *(const uint4*)p; return t.v;
}
__device__ __forceinline__ bf16x8 zfrag() {
    bf16x8 z;
#pragma unroll
    for (int jj = 0; jj < 8; jj++) z[jj] = (__bf16)0.f;
    return z;
}
// ---- L2-bypassing (sc0 sc1) PLAIN loads/stores: same cross-XCD visibility as
// agent-scope atomics (L3 = coherence point) but coalescing + pipelined.
__device__ __forceinline__ void ld16_sc01(const void* p, uint4* d) {
    asm volatile("global_load_dwordx4 %0, %1, off sc0 sc1" : "=v"(*d) : "v"(p));
}
__device__ __forceinline__ void st4_sc01(void* p, unsigned v) {
    asm volatile("global_store_dword %0, %1, off sc0 sc1" :: "v"(p), "v"(v) : "memory");
}
__device__ __forceinline__ void wait_vm0() {
    asm volatile("s_waitcnt vmcnt(0)" ::: "memory");
}
// wave-local LDS fence: all prior DS writes from this wave complete; the
// sched_barrier keeps following LDS reads from being hoisted above (rule #18).
__device__ __forceinline__ void wait_lgkm0() {
    asm volatile("s_waitcnt lgkmcnt(0)" ::: "memory");
    __builtin_amdgcn_sched_barrier(0);
}
// scalar-component register pin (R11 compile fix)
#define PIN32(x) asm volatile("" : "+v"(x))
__device__ __forceinline__ void pin_u4(uint4& u) {
    PIN32(u.x); PIN32(u.y); PIN32(u.z); PIN32(u.w);
}

__device__ __forceinline__ unsigned ald_u32(const void* p) {
    return __hip_atomic_load((const unsigned*)p, __ATOMIC_RELAXED, __HIP_MEMORY_SCOPE_AGENT);
}
__device__ __forceinline__ unsigned bf16_bits(float f) {
    __bf16 h = (__bf16)f; unsigned short s;
    __builtin_memcpy(&s, &h, 2); return (unsigned)s;
}
__device__ __forceinline__ float bf16_lo(unsigned v) {
    unsigned u = (v & 0xffffu) << 16; float f;
    __builtin_memcpy(&f, &u, 4); return f;
}
__device__ __forceinline__ float bf16_hi(unsigned v) {
    unsigned u = v & 0xffff0000u; float f;
    __builtin_memcpy(&f, &u, 4); return f;
}

__device__ __forceinline__ void gl_lds16(const uint4* g, void* l) {
    __builtin_amdgcn_global_load_lds(
        (const __attribute__((address_space(1))) unsigned int*)g,
        (__attribute__((address_space(3))) unsigned int*)l, 16, 0, 0);
}

__device__ __forceinline__ float sigf(float x) {
    return __builtin_amdgcn_rcpf(1.f + __expf(-x));
}
__device__ __forceinline__ float tanhf_fast(float x) {
    return 1.f - 2.f * __builtin_amdgcn_rcpf(1.f + __expf(2.f * x));
}

#define MFMA(A,B,C) C = __builtin_amdgcn_mfma_f32_16x16x32_bf16(A, B, C, 0, 0, 0)

// ---------------------------------------------------------------------------
// pack: [Wx(16,pad 32); Uh(256); Uh2(256)] -> B-fragments. (unchanged)
// ---------------------------------------------------------------------------
__global__ void pack_kernel(const float* __restrict__ Wx, const float* __restrict__ Uh,
                            const float* __restrict__ Uh2, uint4* __restrict__ packW) {
    int tid = blockIdx.x * 256 + threadIdx.x;   // 4*17*48*64 = 208896
    int lane = tid & 63;
    int nt   = (tid >> 6) % 48;
    int kt   = ((tid >> 6) / 48) % 17;
    int a    = (tid >> 6) / (48 * 17);
    int col  = nt * 16 + (lane & 15);
    U4 u;
#pragma unroll
    for (int jj = 0; jj < 8; jj++) {
        int p  = (lane >> 4) * 8 + jj;
        int kk = (kt == 0) ? p : (((p & 1) << 4) | (p >> 1));
        int k  = kt * 32 + kk;
        float v;
        if (k < 16)       v = Wx[(a * 16 + k) * 768 + col];
        else if (k < 32)  v = 0.f;
        else if (k < 288) v = Uh[(a * 256 + (k - 32)) * 768 + col];
        else              v = Uh2[(a * 256 + (k - 288)) * 768 + col];
        u.v[jj] = (__bf16)v;
    }
    packW[tid] = u.u;
}

// xpack[a][i29][j29][m256][q2] = 8 bf16 of patch element k=q*8+jj (unchanged)
__global__ void xpack_kernel(const float* __restrict__ x, uint4* __restrict__ xp) {
    int tid = blockIdx.x * 256 + threadIdx.x;   // 1,722,368
    int q = tid & 1;
    int m = (tid >> 1) & 255;
    int rem = tid >> 9;
    int j = rem % 29;
    int t2 = rem / 29;
    int i = t2 % 29;
    int a = t2 / 29;
    int Ny = 29 - (a & 1), Nx = 29 - ((a >> 1) & 1);
    U4 u;
    if (i < Ny && j < Nx) {
        int y0 = (a & 1) ? (27 - i) : i;
        int x0 = (a & 2) ? (27 - j) : j;
        const float* px = x + m * 1024 + y0 * 32 + x0;
#pragma unroll
        for (int jj = 0; jj < 8; jj++) {
            int k = q * 8 + jj;
            u.v[jj] = (__bf16)px[(k >> 2) * 32 + (k & 3)];
        }
    } else {
#pragma unroll
        for (int jj = 0; jj < 8; jj++) u.v[jj] = (__bf16)0.f;
    }
    xp[tid] = u.u;
}

// ---------------------------------------------------------------------------
// Dataflow persistent kernel (R12 structure; R21 = LDS-scratch hs dedup).
//   G = bx&31 : group (a = G>>3 direction, s8 = G&7 batch-slice of M32)
//   g  = bx>>5: 32-hidden-col split (B for (a,g) in 102 KB LDS, loaded once)
// FABRIC MODEL (R12..R19): the sc0sc1 read stream is service-limited at
// ~4.1 TB/s; dur == bytes/4.1TB/s within 2%. Only traffic reduction helps.
// R21: the 16 hs ld4s per cell re-fetched 64B lines ALREADY transferred by
// the ld16 sweep (stage kt=g is inside the swept 16 KB) -> 4 KB of ~36 KB
// per-cell fabric lines (11%). Dedup via per-wave LDS scratch: each lane
// writes its stage-g fragments (wave-uniform kt==g guard; rule #20 -- no
// runtime reg indexing) into a 2 KB region laid out exactly like the slice,
// wave-local lgkmcnt fence (NO block barrier), then reads the verbatim R12
// ld4 addresses from LDS. Bit-identical values. A/L use disjoint regions
// (+32 KB LDS total = 137216 B; still 1 block/CU, occupancy unchanged).
// Sync protocol, store layout, flags: byte-identical to R12.
// OCCUPANCY (R16/R17): unified-regfile cap ~2 waves/SIMD; 512 thr is max.
// ---------------------------------------------------------------------------
__global__ __launch_bounds__(512, 2) void persist_kernel(
    const float* __restrict__ x, const uint4* __restrict__ xpack,
    const uint4* __restrict__ packW, const float* __restrict__ bias,
    char* __restrict__ hbuf, unsigned* __restrict__ flags)
{
    extern __shared__ __align__(16) unsigned char smem[];   // 137216 B

    int bx = blockIdx.x;
    int G  = bx & 31;
    int g  = bx >> 5;
    int a  = G >> 3, s8 = G & 7;
    int Ny = 29 - (a & 1), Nx = 29 - ((a >> 1) & 1);
    char* hbg = hbuf + (size_t)G * 1425408;
    unsigned* prog = flags + G * 32;
    unsigned* cons = flags + 1024 + G * 32;

    int tid  = threadIdx.x;
    int w8   = tid >> 6;          // wave = strip owner
    int lane = tid & 63;
    int q    = lane >> 4;
    int l16  = lane & 15;

    // per-wave hs scratch: A at +0, L at +2048 (disjoint; no overwrite hazard)
    unsigned char* hscrA = smem + 104448 + (size_t)w8 * 4096;
    unsigned char* hscrL = hscrA + 2048;

    // ---- one-time B preload: 102 chunks x 1 KB ----
    for (int c = w8; c < 102; c += 8) {
        int s  = c / 6;
        int cc = c - s * 6;
        int kt = (s == 16) ? 0 : (s + 1);
        int nt = (cc >> 1) * 16 + 2 * g + (cc & 1);
        gl_lds16(packW + (size_t)(a * 17 + kt) * 3072 + nt * 64 + lane,
                 smem + (size_t)c * 1024);
    }
    __syncthreads();   // the only barrier in the kernel

    const float* ba = bias + a * 768;
    int c0 = g * 32 + l16;
    float bR0 = ba[c0],      bZ0 = ba[256 + c0],      bN0 = ba[512 + c0];
    float bR1 = ba[c0 + 16], bZ1 = ba[256 + c0 + 16], bN1 = ba[512 + c0 + 16];

    // single-lane poll + wave broadcast
    auto wait_ge = [&](unsigned* f, unsigned v) {
        for (;;) {
            unsigned cur = 0;
            if (lane == 0) cur = ald_u32(f);
            cur = __builtin_amdgcn_readfirstlane(cur);
            if ((int)cur >= (int)v) break;
            __builtin_amdgcn_s_sleep(2);
        }
        __asm__ volatile("" ::: "memory");
    };

    // contiguous strip for wave w8
    int sbase = Nx >> 3, srem = Nx & 7;
    int js = w8 * sbase + (w8 < srem ? w8 : srem);
    int je = js + sbase + (w8 < srem ? 1 : 0);   // exclusive

    for (int i = 0; i < Ny; ++i) {
        for (int j = js; j < je; ++j) {
            bool hasA = (i > 0);
            bool hasL = (j > 0);

            // x-stage A fragments (plain cached)
            bf16x8 afx[2];
            if (xpack) {
                const uint4* xpc = xpack + (size_t)((a * 29 + i) * 29 + j) * 512
                                  + (size_t)(s8 * 32) * 2 + q;
#pragma unroll
                for (int mt = 0; mt < 2; mt++) {
                    if (q < 2) afx[mt] = ld_frag(xpc + (mt * 16 + l16) * 2);
                    else       afx[mt] = zfrag();
                }
            } else {
                int y0 = (a & 1) ? (27 - i) : i;
                int x0 = (a & 2) ? (27 - j) : j;
#pragma unroll
                for (int mt = 0; mt < 2; mt++) {
                    if (q < 2) {
                        int m = s8 * 32 + mt * 16 + l16;
                        const float* xp = x + m * 1024 + (y0 + 2 * q) * 32 + x0;
#pragma unroll
                        for (int jj = 0; jj < 8; jj++)
                            afx[mt][jj] = (__bf16)xp[(jj >> 2) * 32 + (jj & 3)];
                    } else afx[mt] = zfrag();
                }
            }

            // ---- dataflow waits ----
            if (hasA) wait_ge(prog + j, 8u * (unsigned)i);
            if (hasL) wait_ge(prog + j - 1, 8u * (unsigned)(i + 1));

            const char* sA = hbg + (size_t)(j * 3 + ((i - 1) % 3)) * 16384;
            const char* sL = hbg + (size_t)((j - 1) * 3 + (i % 3)) * 16384;

            // ---- issue coalesced sc0sc1 ld16 sweeps (full 16 KB slices,
            //      which INCLUDE the hs region; no separate ld4s) ----
            U4 rA[8][2], rL[8][2];
            unsigned hsA[8], hsL[8];
            if (hasA) {
#pragma unroll
                for (int kt = 0; kt < 8; kt++)
#pragma unroll
                    for (int mt = 0; mt < 2; mt++)
                        ld16_sc01(sA + kt * 2048 + (mt * 16 + l16) * 64 + q * 16,
                                  &rA[kt][mt].u);
            }
            if (hasL) {
#pragma unroll
                for (int kt = 0; kt < 8; kt++)
#pragma unroll
                    for (int mt = 0; mt < 2; mt++)
                        ld16_sc01(sL + kt * 2048 + (mt * 16 + l16) * 64 + q * 16,
                                  &rL[kt][mt].u);
            }
            wait_vm0();
            // pin post-wait values (uses below can't be hoisted above the wait)
            if (hasA) {
#pragma unroll
                for (int kt = 0; kt < 8; kt++)
#pragma unroll
                    for (int mt = 0; mt < 2; mt++) pin_u4(rA[kt][mt].u);
            }
            if (hasL) {
#pragma unroll
                for (int kt = 0; kt < 8; kt++)
#pragma unroll
                    for (int mt = 0; mt < 2; mt++) pin_u4(rL[kt][mt].u);
            }

            // ---- hs via per-wave LDS scratch (replaces the 16 sc01 ld4s).
            //      Write stage-g fragments in slice layout; wave-local fence;
            //      read the verbatim R12 ld4 addresses. Bit-identical. ----
            if (hasA) {
#pragma unroll
                for (int kt = 0; kt < 8; kt++)
                    if (kt == g) {   // wave-uniform guard (rule #20)
                        *(uint4*)(hscrA + (size_t)l16 * 64 + q * 16)        = rA[kt][0].u;
                        *(uint4*)(hscrA + (size_t)(16 + l16) * 64 + q * 16) = rA[kt][1].u;
                    }
            }
            if (hasL) {
#pragma unroll
                for (int kt = 0; kt < 8; kt++)
                    if (kt == g) {
                        *(uint4*)(hscrL + (size_t)l16 * 64 + q * 16)        = rL[kt][0].u;
                        *(uint4*)(hscrL + (size_t)(16 + l16) * 64 + q * 16) = rL[kt][1].u;
                    }
            }
            if (hasA || hasL) wait_lgkm0();
            if (hasA) {
#pragma unroll
                for (int mt = 0; mt < 2; mt++)
#pragma unroll
                    for (int e = 0; e < 4; e++)
                        hsA[mt * 4 + e] = *(const unsigned*)
                            (hscrA + (size_t)(mt * 16 + q * 4 + e) * 64 + (size_t)l16 * 4);
            }
            if (hasL) {
#pragma unroll
                for (int mt = 0; mt < 2; mt++)
#pragma unroll
                    for (int e = 0; e < 4; e++)
                        hsL[mt * 4 + e] = *(const unsigned*)
                            (hscrL + (size_t)(mt * 16 + q * 4 + e) * 64 + (size_t)l16 * 4);
            }

            f32x4 acc[2][6];
#pragma unroll
            for (int mt = 0; mt < 2; mt++)
#pragma unroll
                for (int cf = 0; cf < 6; cf++)
#pragma unroll
                    for (int e = 0; e < 4; e++) acc[mt][cf][e] = 0.f;

            // ---- x-stage: r,z into acc[.][0..3]; n-part into tn ----
            f32x4 tn0[2], tn1[2];
            {
                const unsigned char* bb = smem + (size_t)16 * 6144 + lane * 16;
#pragma unroll
                for (int cf = 0; cf < 4; cf++) {
                    bf16x8 bf = ld_frag(bb + cf * 1024);
#pragma unroll
                    for (int mt = 0; mt < 2; mt++) MFMA(afx[mt], bf, acc[mt][cf]);
                }
                bf16x8 bn0 = ld_frag(bb + 4 * 1024);
                bf16x8 bn1 = ld_frag(bb + 5 * 1024);
#pragma unroll
                for (int mt = 0; mt < 2; mt++) {
                    f32x4 z4 = {0.f, 0.f, 0.f, 0.f};
                    tn0[mt] = __builtin_amdgcn_mfma_f32_16x16x32_bf16(afx[mt], bn0, z4, 0, 0, 0);
                    tn1[mt] = __builtin_amdgcn_mfma_f32_16x16x32_bf16(afx[mt], bn1, z4, 0, 0, 0);
                }
            }

            // ---- 16 h-stages ----
            if (hasA) {
#pragma unroll
                for (int s = 0; s < 8; s++) {
                    const unsigned char* bb = smem + (size_t)s * 6144 + lane * 16;
#pragma unroll
                    for (int cf = 0; cf < 6; cf++) {
                        bf16x8 bf = ld_frag(bb + cf * 1024);
#pragma unroll
                        for (int mt = 0; mt < 2; mt++) MFMA(rA[s][mt].v, bf, acc[mt][cf]);
                    }
                }
            }
            if (hasL) {
#pragma unroll
                for (int s = 0; s < 8; s++) {
                    const unsigned char* bb = smem + (size_t)(8 + s) * 6144 + lane * 16;
#pragma unroll
                    for (int cf = 0; cf < 6; cf++) {
                        bf16x8 bf = ld_frag(bb + cf * 1024);
#pragma unroll
                        for (int mt = 0; mt < 2; mt++) MFMA(rL[s][mt].v, bf, acc[mt][cf]);
                    }
                }
            }

            // ---- back-pressure before overwriting slot (j, i%3) ----
            if (j < Nx - 1 && i >= 3) wait_ge(cons + j, 8u * (unsigned)(i - 2));

            // ---- epilogue: gates, state update, coalesced sc0sc1 stores ----
            char* sO = hbg + (size_t)(j * 3 + (i % 3)) * 16384;
#pragma unroll
            for (int mt = 0; mt < 2; mt++) {
#pragma unroll
                for (int e = 0; e < 4; e++) {
                    int m = mt * 16 + q * 4 + e;
                    float rv0 = sigf(acc[mt][0][e] + bR0);
                    float zv0 = sigf(acc[mt][2][e] + bZ0);
                    float nv0 = tanhf_fast(tn0[mt][e] + bN0 + rv0 * acc[mt][4][e]);
                    float rv1 = sigf(acc[mt][1][e] + bR1);
                    float zv1 = sigf(acc[mt][3][e] + bZ1);
                    float nv1 = tanhf_fast(tn1[mt][e] + bN1 + rv1 * acc[mt][5][e]);
                    float hs0 = 0.f, hs1 = 0.f;
                    if (hasA) {
                        unsigned v = hsA[mt * 4 + e];
                        hs0 += bf16_lo(v); hs1 += bf16_hi(v);
                    }
                    if (hasL) {
                        unsigned v = hsL[mt * 4 + e];
                        hs0 += bf16_lo(v); hs1 += bf16_hi(v);
                    }
                    float h0 = (1.f - zv0) * nv0 + 0.5f * zv0 * hs0;
                    float h1 = (1.f - zv1) * nv1 + 0.5f * zv1 * hs1;
                    st4_sc01(sO + (size_t)g * 2048 + (size_t)m * 64 + l16 * 4,
                             bf16_bits(h0) | (bf16_bits(h1) << 16));
                }
            }

            wait_vm0();   // h stores at the L3 coherence point
            if (lane == 0) {
                __hip_atomic_fetch_add(prog + j, 1u, __ATOMIC_RELAXED,
                                       __HIP_MEMORY_SCOPE_AGENT);
                if (hasL)
                    __hip_atomic_fetch_add(cons + j - 1, 1u, __ATOMIC_RELAXED,
                                           __HIP_MEMORY_SCOPE_AGENT);
            }
        }
    }
}

// ---------------------------------------------------------------------------
// Output: logits = hcat @ W_out + b_out, then log_softmax. One wave per batch.
// ---------------------------------------------------------------------------
__global__ __launch_bounds__(64) void out_kernel(const char* __restrict__ hbuf,
    const float* __restrict__ Wout, const float* __restrict__ bout,
    float* __restrict__ out)
{
    int b = blockIdx.x;
    int tt = threadIdx.x;
    float accv[10];
#pragma unroll
    for (int o = 0; o < 10; o++) accv[o] = 0.f;
    for (int it = 0; it < 16; ++it) {
        int k = it * 64 + tt;
        int a = k >> 8, c = k & 255;
        int Ny = 29 - (a & 1), Nx = 29 - ((a >> 1) & 1);
        int G  = a * 8 + (b >> 5);
        int c31 = c & 31;
        int pos = ((c31 & 15) << 1) | (c31 >> 4);
        const __bf16* hp = (const __bf16*)(hbuf + (size_t)G * 1425408
                           + (size_t)((Nx - 1) * 3 + (Ny - 1) % 3) * 16384
                           + (size_t)(c >> 5) * 2048 + (size_t)(b & 31) * 64
                           + (size_t)pos * 2);
        float h = (float)(*hp);
        const float* wr = Wout + k * 10;
#pragma unroll
        for (int o = 0; o < 10; o++) accv[o] += h * wr[o];
    }
#pragma unroll
    for (int off = 32; off > 0; off >>= 1)
#pragma unroll
        for (int o = 0; o < 10; o++) accv[o] += __shfl_down(accv[o], off, 64);
    if (tt == 0) {
        float l[10];
#pragma unroll
        for (int o = 0; o < 10; o++) l[o] = accv[o] + bout[o];
        float mx = l[0];
#pragma unroll
        for (int o = 1; o < 10; o++) mx = fmaxf(mx, l[o]);
        float se = 0.f;
#pragma unroll
        for (int o = 0; o < 10; o++) se += __expf(l[o] - mx);
        float lse = mx + __logf(se);
#pragma unroll
        for (int o = 0; o < 10; o++) out[b * 10 + o] = l[o] - lse;
    }
}

extern "C" void kernel_launch(void* const* d_in, const int* in_sizes, int n_in,
                              void* d_out, int out_size, void* d_ws, size_t ws_size,
                              hipStream_t stream) {
    const float* x    = (const float*)d_in[0];
    const float* Wx   = (const float*)d_in[1];
    const float* Uh   = (const float*)d_in[2];
    const float* Uh2  = (const float*)d_in[3];
    const float* b    = (const float*)d_in[4];
    const float* Wout = (const float*)d_in[5];
    const float* bout = (const float*)d_in[6];
    float* out = (float*)d_out;

    char* ws = (char*)d_ws;
    const size_t PACK_PAD   = 3407872;
    const size_t XPACK_END  = 31457280;     // pack + xpack (padded)
    const size_t HBUF_BYTES = 45613056;     // 32 * 29 * 3 * 16384
    const size_t FLAG_BYTES = 8192;
    bool use_xp = (ws_size >= XPACK_END + HBUF_BYTES + FLAG_BYTES);

    uint4*  packW = (uint4*)ws;
    uint4*  xpack = use_xp ? (uint4*)(ws + PACK_PAD) : nullptr;
    size_t  hbuf_off = use_xp ? XPACK_END : PACK_PAD;
    char*   hbuf  = ws + hbuf_off;
    unsigned* flags = (unsigned*)(ws + hbuf_off + HBUF_BYTES);

    (void)hipFuncSetAttribute((const void*)persist_kernel,
                              hipFuncAttributeMaxDynamicSharedMemorySize, 137216);

    hipMemsetAsync(flags, 0, FLAG_BYTES, stream);
    pack_kernel<<<816, 256, 0, stream>>>(Wx, Uh, Uh2, packW);
    if (use_xp)
        xpack_kernel<<<6728, 256, 0, stream>>>(x, xpack);

    void* args[] = { (void*)&x, (void*)&xpack, (void*)&packW, (void*)&b,
                     (void*)&hbuf, (void*)&flags };
    hipLaunchCooperativeKernel((void*)persist_kernel, dim3(256), dim3(512),
                               args, 137216, stream);

    out_kernel<<<256, 64, 0, stream>>>(hbuf, Wout, bout, out);
}

// Round 10
// 1513.314 us; speedup vs baseline: 1.3565x; 1.3401x over previous
//
#include <hip/hip_runtime.h>

typedef __bf16 bf16x8 __attribute__((ext_vector_type(8)));
typedef float  f32x4  __attribute__((ext_vector_type(4)));

union U4 { uint4 u; bf16x8 v; };

__device__ __forceinline__ bf16x8 ld_frag(const void* p) {
    U4 t; t.u = *(const uint4*)p; return t.v;
}
__device__ __forceinline__ bf16x8 zfrag() {
    bf16x8 z;
#pragma unroll
    for (int jj = 0; jj < 8; jj++) z[jj] = (__bf16)0.f;
    return z;
}
// ---- L2-bypassing (sc0 sc1) PLAIN loads/stores: same cross-XCD visibility as
// agent-scope atomics (L3 = coherence point) but coalescing + pipelined.
__device__ __forceinline__ void ld16_sc01(const void* p, uint4* d) {
    asm volatile("global_load_dwordx4 %0, %1, off sc0 sc1" : "=v"(*d) : "v"(p));
}
__device__ __forceinline__ void ld4_sc01(const void* p, unsigned* d) {
    asm volatile("global_load_dword %0, %1, off sc0 sc1" : "=v"(*d) : "v"(p));
}
__device__ __forceinline__ void st4_sc01(void* p, unsigned v) {
    asm volatile("global_store_dword %0, %1, off sc0 sc1" :: "v"(p), "v"(v) : "memory");
}
__device__ __forceinline__ void wait_vm0() {
    asm volatile("s_waitcnt vmcnt(0)" ::: "memory");
}
// scalar-component register pin (R11 compile fix)
#define PIN32(x) asm volatile("" : "+v"(x))
__device__ __forceinline__ void pin_u4(uint4& u) {
    PIN32(u.x); PIN32(u.y); PIN32(u.z); PIN32(u.w);
}

__device__ __forceinline__ unsigned ald_u32(const void* p) {
    return __hip_atomic_load((const unsigned*)p, __ATOMIC_RELAXED, __HIP_MEMORY_SCOPE_AGENT);
}
__device__ __forceinline__ unsigned bf16_bits(float f) {
    __bf16 h = (__bf16)f; unsigned short s;
    __builtin_memcpy(&s, &h, 2); return (unsigned)s;
}
__device__ __forceinline__ float bf16_lo(unsigned v) {
    unsigned u = (v & 0xffffu) << 16; float f;
    __builtin_memcpy(&f, &u, 4); return f;
}
__device__ __forceinline__ float bf16_hi(unsigned v) {
    unsigned u = v & 0xffff0000u; float f;
    __builtin_memcpy(&f, &u, 4); return f;
}

__device__ __forceinline__ void gl_lds16(const uint4* g, void* l) {
    __builtin_amdgcn_global_load_lds(
        (const __attribute__((address_space(1))) unsigned int*)g,
        (__attribute__((address_space(3))) unsigned int*)l, 16, 0, 0);
}

__device__ __forceinline__ float sigf(float x) {
    return __builtin_amdgcn_rcpf(1.f + __expf(-x));
}
__device__ __forceinline__ float tanhf_fast(float x) {
    return 1.f - 2.f * __builtin_amdgcn_rcpf(1.f + __expf(2.f * x));
}

#define MFMA(A,B,C) C = __builtin_amdgcn_mfma_f32_16x16x32_bf16(A, B, C, 0, 0, 0)

// ---------------------------------------------------------------------------
// pack: [Wx(16,pad 32); Uh(256); Uh2(256)] -> B-fragments. (unchanged)
// ---------------------------------------------------------------------------
__global__ void pack_kernel(const float* __restrict__ Wx, const float* __restrict__ Uh,
                            const float* __restrict__ Uh2, uint4* __restrict__ packW) {
    int tid = blockIdx.x * 256 + threadIdx.x;   // 4*17*48*64 = 208896
    int lane = tid & 63;
    int nt   = (tid >> 6) % 48;
    int kt   = ((tid >> 6) / 48) % 17;
    int a    = (tid >> 6) / (48 * 17);
    int col  = nt * 16 + (lane & 15);
    U4 u;
#pragma unroll
    for (int jj = 0; jj < 8; jj++) {
        int p  = (lane >> 4) * 8 + jj;
        int kk = (kt == 0) ? p : (((p & 1) << 4) | (p >> 1));
        int k  = kt * 32 + kk;
        float v;
        if (k < 16)       v = Wx[(a * 16 + k) * 768 + col];
        else if (k < 32)  v = 0.f;
        else if (k < 288) v = Uh[(a * 256 + (k - 32)) * 768 + col];
        else              v = Uh2[(a * 256 + (k - 288)) * 768 + col];
        u.v[jj] = (__bf16)v;
    }
    packW[tid] = u.u;
}

// xpack[a][i29][j29][m256][q2] = 8 bf16 of patch element k=q*8+jj (unchanged)
__global__ void xpack_kernel(const float* __restrict__ x, uint4* __restrict__ xp) {
    int tid = blockIdx.x * 256 + threadIdx.x;   // 1,722,368
    int q = tid & 1;
    int m = (tid >> 1) & 255;
    int rem = tid >> 9;
    int j = rem % 29;
    int t2 = rem / 29;
    int i = t2 % 29;
    int a = t2 / 29;
    int Ny = 29 - (a & 1), Nx = 29 - ((a >> 1) & 1);
    U4 u;
    if (i < Ny && j < Nx) {
        int y0 = (a & 1) ? (27 - i) : i;
        int x0 = (a & 2) ? (27 - j) : j;
        const float* px = x + m * 1024 + y0 * 32 + x0;
#pragma unroll
        for (int jj = 0; jj < 8; jj++) {
            int k = q * 8 + jj;
            u.v[jj] = (__bf16)px[(k >> 2) * 32 + (k & 3)];
        }
    } else {
#pragma unroll
        for (int jj = 0; jj < 8; jj++) u.v[jj] = (__bf16)0.f;
    }
    xp[tid] = u.u;
}

// ---------------------------------------------------------------------------
// Dataflow persistent kernel (R12 cell code; R22 = ring depth D + padded flags).
//   G = bx&31 : group (a = G>>3 direction, s8 = G&7 batch-slice of M32)
//   g  = bx>>5: 32-hidden-col split (B for (a,g) in 102 KB LDS, loaded once)
// DIAGNOSIS (R12..R21): per-wave serial cell-step = ~43K cy vs ~6.5K intrinsic
// chain; bandwidth models falsified (hs-dedup null x2, L2-localization dead,
// occupancy capped at 512 thr by unified regfile). The gap is JITTER COUPLING:
// the 3-slot ring's back-pressure (cons[j] >= 8(i-2)) ties all 29 cols x 8
// blocks of a group into near-lockstep; every global step advances at the max
// of ~230 jittery chains. R22 loosens the formation:
//   - ring depth D=6 (ws-adaptive; D=3 fallback = exact R12): back-pressure
//     cons[j] >= 8(i-(D-1)) gives 5 rows of slack to absorb transients.
//     Strictly looser thresholds -> correctness/deadlock-freedom inherited.
//   - fstride=16: each prog/cons counter on its own 64B line (was: all 29
//     cols of a group sharing one 128B line, RMW'd + polled by 64 waves).
// Cell schedule, loads/stores, flag semantics: byte-identical to R12.
// hbuf per group: [j29][slotD][kt8][m32][c32perm] bf16 (slice 16 KB).
// ---------------------------------------------------------------------------
__global__ __launch_bounds__(512, 2) void persist_kernel(
    const float* __restrict__ x, const uint4* __restrict__ xpack,
    const uint4* __restrict__ packW, const float* __restrict__ bias,
    char* __restrict__ hbuf, unsigned* __restrict__ flags,
    int D, int fstride)
{
    extern __shared__ __align__(16) unsigned char smem[];   // 104448 B

    int bx = blockIdx.x;
    int G  = bx & 31;
    int g  = bx >> 5;
    int a  = G >> 3, s8 = G & 7;
    int Ny = 29 - (a & 1), Nx = 29 - ((a >> 1) & 1);
    size_t gslice = (size_t)29 * D * 16384;
    char* hbg = hbuf + (size_t)G * gslice;
    unsigned* prog = flags + (size_t)(G * 32) * fstride;
    unsigned* cons = flags + (size_t)(1024 + G * 32) * fstride;

    int tid  = threadIdx.x;
    int w8   = tid >> 6;          // wave = strip owner
    int lane = tid & 63;
    int q    = lane >> 4;
    int l16  = lane & 15;

    // ---- one-time B preload: 102 chunks x 1 KB ----
    for (int c = w8; c < 102; c += 8) {
        int s  = c / 6;
        int cc = c - s * 6;
        int kt = (s == 16) ? 0 : (s + 1);
        int nt = (cc >> 1) * 16 + 2 * g + (cc & 1);
        gl_lds16(packW + (size_t)(a * 17 + kt) * 3072 + nt * 64 + lane,
                 smem + (size_t)c * 1024);
    }
    __syncthreads();   // the only barrier in the kernel

    const float* ba = bias + a * 768;
    int c0 = g * 32 + l16;
    float bR0 = ba[c0],      bZ0 = ba[256 + c0],      bN0 = ba[512 + c0];
    float bR1 = ba[c0 + 16], bZ1 = ba[256 + c0 + 16], bN1 = ba[512 + c0 + 16];

    // single-lane poll + wave broadcast
    auto wait_ge = [&](unsigned* f, unsigned v) {
        for (;;) {
            unsigned cur = 0;
            if (lane == 0) cur = ald_u32(f);
            cur = __builtin_amdgcn_readfirstlane(cur);
            if ((int)cur >= (int)v) break;
            __builtin_amdgcn_s_sleep(2);
        }
        __asm__ volatile("" ::: "memory");
    };

    // contiguous strip for wave w8
    int sbase = Nx >> 3, srem = Nx & 7;
    int js = w8 * sbase + (w8 < srem ? w8 : srem);
    int je = js + sbase + (w8 < srem ? 1 : 0);   // exclusive

    for (int i = 0; i < Ny; ++i) {
        int slot  = i % D;
        int slotA = (i - 1) % D;   // valid only when i>0 (guarded by hasA)
        for (int j = js; j < je; ++j) {
            bool hasA = (i > 0);
            bool hasL = (j > 0);

            // x-stage A fragments (plain cached)
            bf16x8 afx[2];
            if (xpack) {
                const uint4* xpc = xpack + (size_t)((a * 29 + i) * 29 + j) * 512
                                  + (size_t)(s8 * 32) * 2 + q;
#pragma unroll
                for (int mt = 0; mt < 2; mt++) {
                    if (q < 2) afx[mt] = ld_frag(xpc + (mt * 16 + l16) * 2);
                    else       afx[mt] = zfrag();
                }
            } else {
                int y0 = (a & 1) ? (27 - i) : i;
                int x0 = (a & 2) ? (27 - j) : j;
#pragma unroll
                for (int mt = 0; mt < 2; mt++) {
                    if (q < 2) {
                        int m = s8 * 32 + mt * 16 + l16;
                        const float* xp = x + m * 1024 + (y0 + 2 * q) * 32 + x0;
#pragma unroll
                        for (int jj = 0; jj < 8; jj++)
                            afx[mt][jj] = (__bf16)xp[(jj >> 2) * 32 + (jj & 3)];
                    } else afx[mt] = zfrag();
                }
            }

            // ---- dataflow waits ----
            if (hasA) wait_ge(prog + (size_t)j * fstride, 8u * (unsigned)i);
            if (hasL) wait_ge(prog + (size_t)(j - 1) * fstride, 8u * (unsigned)(i + 1));

            const char* sA = hbg + ((size_t)j * D + slotA) * 16384;
            const char* sL = hbg + ((size_t)(j - 1) * D + slot) * 16384;

            // ---- issue coalesced sc0sc1 loads for all A fragments ----
            U4 rA[8][2], rL[8][2];
            unsigned hsA[8], hsL[8];
            if (hasA) {
#pragma unroll
                for (int kt = 0; kt < 8; kt++)
#pragma unroll
                    for (int mt = 0; mt < 2; mt++)
                        ld16_sc01(sA + kt * 2048 + (mt * 16 + l16) * 64 + q * 16,
                                  &rA[kt][mt].u);
#pragma unroll
                for (int mt = 0; mt < 2; mt++)
#pragma unroll
                    for (int e = 0; e < 4; e++)
                        ld4_sc01(sA + g * 2048 + (mt * 16 + q * 4 + e) * 64 + l16 * 4,
                                 &hsA[mt * 4 + e]);
            }
            if (hasL) {
#pragma unroll
                for (int kt = 0; kt < 8; kt++)
#pragma unroll
                    for (int mt = 0; mt < 2; mt++)
                        ld16_sc01(sL + kt * 2048 + (mt * 16 + l16) * 64 + q * 16,
                                  &rL[kt][mt].u);
#pragma unroll
                for (int mt = 0; mt < 2; mt++)
#pragma unroll
                    for (int e = 0; e < 4; e++)
                        ld4_sc01(sL + g * 2048 + (mt * 16 + q * 4 + e) * 64 + l16 * 4,
                                 &hsL[mt * 4 + e]);
            }
            wait_vm0();
            // pin post-wait values (uses below can't be hoisted above the wait)
            if (hasA) {
#pragma unroll
                for (int kt = 0; kt < 8; kt++)
#pragma unroll
                    for (int mt = 0; mt < 2; mt++) pin_u4(rA[kt][mt].u);
#pragma unroll
                for (int e = 0; e < 8; e++) PIN32(hsA[e]);
            }
            if (hasL) {
#pragma unroll
                for (int kt = 0; kt < 8; kt++)
#pragma unroll
                    for (int mt = 0; mt < 2; mt++) pin_u4(rL[kt][mt].u);
#pragma unroll
                for (int e = 0; e < 8; e++) PIN32(hsL[e]);
            }

            f32x4 acc[2][6];
#pragma unroll
            for (int mt = 0; mt < 2; mt++)
#pragma unroll
                for (int cf = 0; cf < 6; cf++)
#pragma unroll
                    for (int e = 0; e < 4; e++) acc[mt][cf][e] = 0.f;

            // ---- x-stage: r,z into acc[.][0..3]; n-part into tn ----
            f32x4 tn0[2], tn1[2];
            {
                const unsigned char* bb = smem + (size_t)16 * 6144 + lane * 16;
#pragma unroll
                for (int cf = 0; cf < 4; cf++) {
                    bf16x8 bf = ld_frag(bb + cf * 1024);
#pragma unroll
                    for (int mt = 0; mt < 2; mt++) MFMA(afx[mt], bf, acc[mt][cf]);
                }
                bf16x8 bn0 = ld_frag(bb + 4 * 1024);
                bf16x8 bn1 = ld_frag(bb + 5 * 1024);
#pragma unroll
                for (int mt = 0; mt < 2; mt++) {
                    f32x4 z4 = {0.f, 0.f, 0.f, 0.f};
                    tn0[mt] = __builtin_amdgcn_mfma_f32_16x16x32_bf16(afx[mt], bn0, z4, 0, 0, 0);
                    tn1[mt] = __builtin_amdgcn_mfma_f32_16x16x32_bf16(afx[mt], bn1, z4, 0, 0, 0);
                }
            }

            // ---- 16 h-stages ----
            if (hasA) {
#pragma unroll
                for (int s = 0; s < 8; s++) {
                    const unsigned char* bb = smem + (size_t)s * 6144 + lane * 16;
#pragma unroll
                    for (int cf = 0; cf < 6; cf++) {
                        bf16x8 bf = ld_frag(bb + cf * 1024);
#pragma unroll
                        for (int mt = 0; mt < 2; mt++) MFMA(rA[s][mt].v, bf, acc[mt][cf]);
                    }
                }
            }
            if (hasL) {
#pragma unroll
                for (int s = 0; s < 8; s++) {
                    const unsigned char* bb = smem + (size_t)(8 + s) * 6144 + lane * 16;
#pragma unroll
                    for (int cf = 0; cf < 6; cf++) {
                        bf16x8 bf = ld_frag(bb + cf * 1024);
#pragma unroll
                        for (int mt = 0; mt < 2; mt++) MFMA(rL[s][mt].v, bf, acc[mt][cf]);
                    }
                }
            }

            // ---- back-pressure before overwriting slot (j, i%D) ----
            if (j < Nx - 1 && i >= D)
                wait_ge(cons + (size_t)j * fstride, 8u * (unsigned)(i - (D - 1)));

            // ---- epilogue: gates, state update, coalesced sc0sc1 stores ----
            char* sO = hbg + ((size_t)j * D + slot) * 16384;
#pragma unroll
            for (int mt = 0; mt < 2; mt++) {
#pragma unroll
                for (int e = 0; e < 4; e++) {
                    int m = mt * 16 + q * 4 + e;
                    float rv0 = sigf(acc[mt][0][e] + bR0);
                    float zv0 = sigf(acc[mt][2][e] + bZ0);
                    float nv0 = tanhf_fast(tn0[mt][e] + bN0 + rv0 * acc[mt][4][e]);
                    float rv1 = sigf(acc[mt][1][e] + bR1);
                    float zv1 = sigf(acc[mt][3][e] + bZ1);
                    float nv1 = tanhf_fast(tn1[mt][e] + bN1 + rv1 * acc[mt][5][e]);
                    float hs0 = 0.f, hs1 = 0.f;
                    if (hasA) {
                        unsigned v = hsA[mt * 4 + e];
                        hs0 += bf16_lo(v); hs1 += bf16_hi(v);
                    }
                    if (hasL) {
                        unsigned v = hsL[mt * 4 + e];
                        hs0 += bf16_lo(v); hs1 += bf16_hi(v);
                    }
                    float h0 = (1.f - zv0) * nv0 + 0.5f * zv0 * hs0;
                    float h1 = (1.f - zv1) * nv1 + 0.5f * zv1 * hs1;
                    st4_sc01(sO + (size_t)g * 2048 + (size_t)m * 64 + l16 * 4,
                             bf16_bits(h0) | (bf16_bits(h1) << 16));
                }
            }

            wait_vm0();   // h stores at the L3 coherence point
            if (lane == 0) {
                __hip_atomic_fetch_add(prog + (size_t)j * fstride, 1u, __ATOMIC_RELAXED,
                                       __HIP_MEMORY_SCOPE_AGENT);
                if (hasL)
                    __hip_atomic_fetch_add(cons + (size_t)(j - 1) * fstride, 1u,
                                           __ATOMIC_RELAXED, __HIP_MEMORY_SCOPE_AGENT);
            }
        }
    }
}

// ---------------------------------------------------------------------------
// Output: logits = hcat @ W_out + b_out, then log_softmax. One wave per batch.
// ---------------------------------------------------------------------------
__global__ __launch_bounds__(64) void out_kernel(const char* __restrict__ hbuf,
    const float* __restrict__ Wout, const float* __restrict__ bout,
    float* __restrict__ out, int D)
{
    int b = blockIdx.x;
    int tt = threadIdx.x;
    size_t gslice = (size_t)29 * D * 16384;
    float accv[10];
#pragma unroll
    for (int o = 0; o < 10; o++) accv[o] = 0.f;
    for (int it = 0; it < 16; ++it) {
        int k = it * 64 + tt;
        int a = k >> 8, c = k & 255;
        int Ny = 29 - (a & 1), Nx = 29 - ((a >> 1) & 1);
        int G  = a * 8 + (b >> 5);
        int c31 = c & 31;
        int pos = ((c31 & 15) << 1) | (c31 >> 4);
        const __bf16* hp = (const __bf16*)(hbuf + (size_t)G * gslice
                           + ((size_t)(Nx - 1) * D + (Ny - 1) % D) * 16384
                           + (size_t)(c >> 5) * 2048 + (size_t)(b & 31) * 64
                           + (size_t)pos * 2);
        float h = (float)(*hp);
        const float* wr = Wout + k * 10;
#pragma unroll
        for (int o = 0; o < 10; o++) accv[o] += h * wr[o];
    }
#pragma unroll
    for (int off = 32; off > 0; off >>= 1)
#pragma unroll
        for (int o = 0; o < 10; o++) accv[o] += __shfl_down(accv[o], off, 64);
    if (tt == 0) {
        float l[10];
#pragma unroll
        for (int o = 0; o < 10; o++) l[o] = accv[o] + bout[o];
        float mx = l[0];
#pragma unroll
        for (int o = 1; o < 10; o++) mx = fmaxf(mx, l[o]);
        float se = 0.f;
#pragma unroll
        for (int o = 0; o < 10; o++) se += __expf(l[o] - mx);
        float lse = mx + __logf(se);
#pragma unroll
        for (int o = 0; o < 10; o++) out[b * 10 + o] = l[o] - lse;
    }
}

extern "C" void kernel_launch(void* const* d_in, const int* in_sizes, int n_in,
                              void* d_out, int out_size, void* d_ws, size_t ws_size,
                              hipStream_t stream) {
    const float* x    = (const float*)d_in[0];
    const float* Wx   = (const float*)d_in[1];
    const float* Uh   = (const float*)d_in[2];
    const float* Uh2  = (const float*)d_in[3];
    const float* b    = (const float*)d_in[4];
    const float* Wout = (const float*)d_in[5];
    const float* bout = (const float*)d_in[6];
    float* out = (float*)d_out;

    char* ws = (char*)d_ws;
    const size_t PACK_PAD  = 3407872;
    const size_t XPACK_END = 31457280;       // pack + xpack (padded)
    const size_t FLAGS_PAD = 131072;         // 2048 counters x 64B (fstride 16)
    const size_t FLAGS_R12 = 8192;           // fstride 1 (exact R12)
    auto hbytes = [](int d) { return (size_t)32 * 29 * d * 16384; };

    // tiered layout: prefer D=6 + padded flags; degrade gracefully.
    bool use_xp; size_t hbuf_off; int D; int fstride; size_t flag_bytes;
    if (ws_size >= XPACK_END + hbytes(6) + FLAGS_PAD) {
        use_xp = true;  hbuf_off = XPACK_END; D = 6; fstride = 16; flag_bytes = FLAGS_PAD;
    } else if (ws_size >= XPACK_END + hbytes(3) + FLAGS_PAD) {
        use_xp = true;  hbuf_off = XPACK_END; D = 3; fstride = 16; flag_bytes = FLAGS_PAD;
    } else if (ws_size >= XPACK_END + hbytes(3) + FLAGS_R12) {
        use_xp = true;  hbuf_off = XPACK_END; D = 3; fstride = 1;  flag_bytes = FLAGS_R12;
    } else {
        use_xp = false; hbuf_off = PACK_PAD;  D = 3; fstride = 1;  flag_bytes = FLAGS_R12;
    }

    uint4*  packW = (uint4*)ws;
    uint4*  xpack = use_xp ? (uint4*)(ws + PACK_PAD) : nullptr;
    char*   hbuf  = ws + hbuf_off;
    unsigned* flags = (unsigned*)(ws + hbuf_off + hbytes(D));

    (void)hipFuncSetAttribute((const void*)persist_kernel,
                              hipFuncAttributeMaxDynamicSharedMemorySize, 104448);

    hipMemsetAsync(flags, 0, flag_bytes, stream);
    pack_kernel<<<816, 256, 0, stream>>>(Wx, Uh, Uh2, packW);
    if (use_xp)
        xpack_kernel<<<6728, 256, 0, stream>>>(x, xpack);

    void* args[] = { (void*)&x, (void*)&xpack, (void*)&packW, (void*)&b,
                     (void*)&hbuf, (void*)&flags, (void*)&D, (void*)&fstride };
    hipLaunchCooperativeKernel((void*)persist_kernel, dim3(256), dim3(512),
                               args, 104448, stream);

    out_kernel<<<256, 64, 0, stream>>>(hbuf, Wout, bout, out, D);
}

// Round 11
// 1352.642 us; speedup vs baseline: 1.5177x; 1.1188x over previous
//
#include <hip/hip_runtime.h>

typedef __bf16 bf16x8 __attribute__((ext_vector_type(8)));
typedef float  f32x4  __attribute__((ext_vector_type(4)));

union U4 { uint4 u; bf16x8 v; };

__device__ __forceinline__ bf16x8 ld_frag(const void* p) {
    U4 t; t.u = *(const uint4*)p; return t.v;
}
__device__ __forceinline__ bf16x8 zfrag() {
    bf16x8 z;
#pragma unroll
    for (int jj = 0; jj < 8; jj++) z[jj] = (__bf16)0.f;
    return z;
}
// ---- L2-bypassing (sc0 sc1) PLAIN loads/stores: same cross-XCD visibility as
// agent-scope atomics (L3 = coherence point) but coalescing + pipelined.
__device__ __forceinline__ void ld16_sc01(const void* p, uint4* d) {
    asm volatile("global_load_dwordx4 %0, %1, off sc0 sc1" : "=v"(*d) : "v"(p));
}
__device__ __forceinline__ void ld4_sc01(const void* p, unsigned* d) {
    asm volatile("global_load_dword %0, %1, off sc0 sc1" : "=v"(*d) : "v"(p));
}
__device__ __forceinline__ void st4_sc01(void* p, unsigned v) {
    asm volatile("global_store_dword %0, %1, off sc0 sc1" :: "v"(p), "v"(v) : "memory");
}
__device__ __forceinline__ void wait_vm0() {
    asm volatile("s_waitcnt vmcnt(0)" ::: "memory");
}
// scalar-component register pin (R11 compile fix)
#define PIN32(x) asm volatile("" : "+v"(x))
__device__ __forceinline__ void pin_u4(uint4& u) {
    PIN32(u.x); PIN32(u.y); PIN32(u.z); PIN32(u.w);
}

__device__ __forceinline__ unsigned ald_u32(const void* p) {
    return __hip_atomic_load((const unsigned*)p, __ATOMIC_RELAXED, __HIP_MEMORY_SCOPE_AGENT);
}
__device__ __forceinline__ unsigned bf16_bits(float f) {
    __bf16 h = (__bf16)f; unsigned short s;
    __builtin_memcpy(&s, &h, 2); return (unsigned)s;
}
__device__ __forceinline__ float bf16_lo(unsigned v) {
    unsigned u = (v & 0xffffu) << 16; float f;
    __builtin_memcpy(&f, &u, 4); return f;
}
__device__ __forceinline__ float bf16_hi(unsigned v) {
    unsigned u = v & 0xffff0000u; float f;
    __builtin_memcpy(&f, &u, 4); return f;
}

__device__ __forceinline__ void gl_lds16(const uint4* g, void* l) {
    __builtin_amdgcn_global_load_lds(
        (const __attribute__((address_space(1))) unsigned int*)g,
        (__attribute__((address_space(3))) unsigned int*)l, 16, 0, 0);
}

__device__ __forceinline__ float sigf(float x) {
    return __builtin_amdgcn_rcpf(1.f + __expf(-x));
}
__device__ __forceinline__ float tanhf_fast(float x) {
    return 1.f - 2.f * __builtin_amdgcn_rcpf(1.f + __expf(2.f * x));
}

#define MFMA(A,B,C) C = __builtin_amdgcn_mfma_f32_16x16x32_bf16(A, B, C, 0, 0, 0)

// ---------------------------------------------------------------------------
// pack: [Wx(16,pad 32); Uh(256); Uh2(256)] -> B-fragments. (unchanged)
// ---------------------------------------------------------------------------
__global__ void pack_kernel(const float* __restrict__ Wx, const float* __restrict__ Uh,
                            const float* __restrict__ Uh2, uint4* __restrict__ packW) {
    int tid = blockIdx.x * 256 + threadIdx.x;   // 4*17*48*64 = 208896
    int lane = tid & 63;
    int nt   = (tid >> 6) % 48;
    int kt   = ((tid >> 6) / 48) % 17;
    int a    = (tid >> 6) / (48 * 17);
    int col  = nt * 16 + (lane & 15);
    U4 u;
#pragma unroll
    for (int jj = 0; jj < 8; jj++) {
        int p  = (lane >> 4) * 8 + jj;
        int kk = (kt == 0) ? p : (((p & 1) << 4) | (p >> 1));
        int k  = kt * 32 + kk;
        float v;
        if (k < 16)       v = Wx[(a * 16 + k) * 768 + col];
        else if (k < 32)  v = 0.f;
        else if (k < 288) v = Uh[(a * 256 + (k - 32)) * 768 + col];
        else              v = Uh2[(a * 256 + (k - 288)) * 768 + col];
        u.v[jj] = (__bf16)v;
    }
    packW[tid] = u.u;
}

// xpack[a][i29][j29][m256][q2] = 8 bf16 of patch element k=q*8+jj (unchanged)
__global__ void xpack_kernel(const float* __restrict__ x, uint4* __restrict__ xp) {
    int tid = blockIdx.x * 256 + threadIdx.x;   // 1,722,368
    int q = tid & 1;
    int m = (tid >> 1) & 255;
    int rem = tid >> 9;
    int j = rem % 29;
    int t2 = rem / 29;
    int i = t2 % 29;
    int a = t2 / 29;
    int Ny = 29 - (a & 1), Nx = 29 - ((a >> 1) & 1);
    U4 u;
    if (i < Ny && j < Nx) {
        int y0 = (a & 1) ? (27 - i) : i;
        int x0 = (a & 2) ? (27 - j) : j;
        const float* px = x + m * 1024 + y0 * 32 + x0;
#pragma unroll
        for (int jj = 0; jj < 8; jj++) {
            int k = q * 8 + jj;
            u.v[jj] = (__bf16)px[(k >> 2) * 32 + (k & 3)];
        }
    } else {
#pragma unroll
        for (int jj = 0; jj < 8; jj++) u.v[jj] = (__bf16)0.f;
    }
    xp[tid] = u.u;
}

// ---------------------------------------------------------------------------
// Dataflow persistent kernel (R12 cell code; R22 ring-D + padded flags = WIN
// 1870->1513us, MfmaUtil 14->21.6; R23 = deeper ring + faster poll).
//   G = bx&31 : group (a = G>>3 direction, s8 = G&7 batch-slice of M32)
//   g  = bx>>5: 32-hidden-col split (B for (a,g) in 102 KB LDS, loaded once)
// MODEL (validated by R22): per-wave cell-step was jitter-coupled through the
// 3-slot ring's back-pressure -- all 29 cols x 8 blocks advanced at the max
// of ~230 chains. Slack (D) + per-counter 64B lines (fstride=16) decouple it.
// R23 probes whether depth is still binding: D up to 12 (ws-tiered; every
// tier degrades to the proven R22/R12 configs; thresholds only get looser ->
// correctness/deadlock-freedom inherited), and s_sleep(2)->(1) halves flag
// discovery latency on the critical hop.
// Cell schedule, loads/stores, flag semantics: byte-identical to R12.
// hbuf per group: [j29][slotD][kt8][m32][c32perm] bf16 (slice 16 KB).
// OCCUPANCY (R16/R17): unified-regfile cap ~2 waves/SIMD; 512 thr is max.
// ---------------------------------------------------------------------------
__global__ __launch_bounds__(512, 2) void persist_kernel(
    const float* __restrict__ x, const uint4* __restrict__ xpack,
    const uint4* __restrict__ packW, const float* __restrict__ bias,
    char* __restrict__ hbuf, unsigned* __restrict__ flags,
    int D, int fstride)
{
    extern __shared__ __align__(16) unsigned char smem[];   // 104448 B

    int bx = blockIdx.x;
    int G  = bx & 31;
    int g  = bx >> 5;
    int a  = G >> 3, s8 = G & 7;
    int Ny = 29 - (a & 1), Nx = 29 - ((a >> 1) & 1);
    size_t gslice = (size_t)29 * D * 16384;
    char* hbg = hbuf + (size_t)G * gslice;
    unsigned* prog = flags + (size_t)(G * 32) * fstride;
    unsigned* cons = flags + (size_t)(1024 + G * 32) * fstride;

    int tid  = threadIdx.x;
    int w8   = tid >> 6;          // wave = strip owner
    int lane = tid & 63;
    int q    = lane >> 4;
    int l16  = lane & 15;

    // ---- one-time B preload: 102 chunks x 1 KB ----
    for (int c = w8; c < 102; c += 8) {
        int s  = c / 6;
        int cc = c - s * 6;
        int kt = (s == 16) ? 0 : (s + 1);
        int nt = (cc >> 1) * 16 + 2 * g + (cc & 1);
        gl_lds16(packW + (size_t)(a * 17 + kt) * 3072 + nt * 64 + lane,
                 smem + (size_t)c * 1024);
    }
    __syncthreads();   // the only barrier in the kernel

    const float* ba = bias + a * 768;
    int c0 = g * 32 + l16;
    float bR0 = ba[c0],      bZ0 = ba[256 + c0],      bN0 = ba[512 + c0];
    float bR1 = ba[c0 + 16], bZ1 = ba[256 + c0 + 16], bN1 = ba[512 + c0 + 16];

    // single-lane poll + wave broadcast (sleep(1): faster discovery; padded
    // flag lines keep the extra poll traffic contention-free)
    auto wait_ge = [&](unsigned* f, unsigned v) {
        for (;;) {
            unsigned cur = 0;
            if (lane == 0) cur = ald_u32(f);
            cur = __builtin_amdgcn_readfirstlane(cur);
            if ((int)cur >= (int)v) break;
            __builtin_amdgcn_s_sleep(1);
        }
        __asm__ volatile("" ::: "memory");
    };

    // contiguous strip for wave w8
    int sbase = Nx >> 3, srem = Nx & 7;
    int js = w8 * sbase + (w8 < srem ? w8 : srem);
    int je = js + sbase + (w8 < srem ? 1 : 0);   // exclusive

    for (int i = 0; i < Ny; ++i) {
        int slot  = i % D;
        int slotA = (i - 1) % D;   // valid only when i>0 (guarded by hasA)
        for (int j = js; j < je; ++j) {
            bool hasA = (i > 0);
            bool hasL = (j > 0);

            // x-stage A fragments (plain cached)
            bf16x8 afx[2];
            if (xpack) {
                const uint4* xpc = xpack + (size_t)((a * 29 + i) * 29 + j) * 512
                                  + (size_t)(s8 * 32) * 2 + q;
#pragma unroll
                for (int mt = 0; mt < 2; mt++) {
                    if (q < 2) afx[mt] = ld_frag(xpc + (mt * 16 + l16) * 2);
                    else       afx[mt] = zfrag();
                }
            } else {
                int y0 = (a & 1) ? (27 - i) : i;
                int x0 = (a & 2) ? (27 - j) : j;
#pragma unroll
                for (int mt = 0; mt < 2; mt++) {
                    if (q < 2) {
                        int m = s8 * 32 + mt * 16 + l16;
                        const float* xp = x + m * 1024 + (y0 + 2 * q) * 32 + x0;
#pragma unroll
                        for (int jj = 0; jj < 8; jj++)
                            afx[mt][jj] = (__bf16)xp[(jj >> 2) * 32 + (jj & 3)];
                    } else afx[mt] = zfrag();
                }
            }

            // ---- dataflow waits ----
            if (hasA) wait_ge(prog + (size_t)j * fstride, 8u * (unsigned)i);
            if (hasL) wait_ge(prog + (size_t)(j - 1) * fstride, 8u * (unsigned)(i + 1));

            const char* sA = hbg + ((size_t)j * D + slotA) * 16384;
            const char* sL = hbg + ((size_t)(j - 1) * D + slot) * 16384;

            // ---- issue coalesced sc0sc1 loads for all A fragments ----
            U4 rA[8][2], rL[8][2];
            unsigned hsA[8], hsL[8];
            if (hasA) {
#pragma unroll
                for (int kt = 0; kt < 8; kt++)
#pragma unroll
                    for (int mt = 0; mt < 2; mt++)
                        ld16_sc01(sA + kt * 2048 + (mt * 16 + l16) * 64 + q * 16,
                                  &rA[kt][mt].u);
#pragma unroll
                for (int mt = 0; mt < 2; mt++)
#pragma unroll
                    for (int e = 0; e < 4; e++)
                        ld4_sc01(sA + g * 2048 + (mt * 16 + q * 4 + e) * 64 + l16 * 4,
                                 &hsA[mt * 4 + e]);
            }
            if (hasL) {
#pragma unroll
                for (int kt = 0; kt < 8; kt++)
#pragma unroll
                    for (int mt = 0; mt < 2; mt++)
                        ld16_sc01(sL + kt * 2048 + (mt * 16 + l16) * 64 + q * 16,
                                  &rL[kt][mt].u);
#pragma unroll
                for (int mt = 0; mt < 2; mt++)
#pragma unroll
                    for (int e = 0; e < 4; e++)
                        ld4_sc01(sL + g * 2048 + (mt * 16 + q * 4 + e) * 64 + l16 * 4,
                                 &hsL[mt * 4 + e]);
            }
            wait_vm0();
            // pin post-wait values (uses below can't be hoisted above the wait)
            if (hasA) {
#pragma unroll
                for (int kt = 0; kt < 8; kt++)
#pragma unroll
                    for (int mt = 0; mt < 2; mt++) pin_u4(rA[kt][mt].u);
#pragma unroll
                for (int e = 0; e < 8; e++) PIN32(hsA[e]);
            }
            if (hasL) {
#pragma unroll
                for (int kt = 0; kt < 8; kt++)
#pragma unroll
                    for (int mt = 0; mt < 2; mt++) pin_u4(rL[kt][mt].u);
#pragma unroll
                for (int e = 0; e < 8; e++) PIN32(hsL[e]);
            }

            f32x4 acc[2][6];
#pragma unroll
            for (int mt = 0; mt < 2; mt++)
#pragma unroll
                for (int cf = 0; cf < 6; cf++)
#pragma unroll
                    for (int e = 0; e < 4; e++) acc[mt][cf][e] = 0.f;

            // ---- x-stage: r,z into acc[.][0..3]; n-part into tn ----
            f32x4 tn0[2], tn1[2];
            {
                const unsigned char* bb = smem + (size_t)16 * 6144 + lane * 16;
#pragma unroll
                for (int cf = 0; cf < 4; cf++) {
                    bf16x8 bf = ld_frag(bb + cf * 1024);
#pragma unroll
                    for (int mt = 0; mt < 2; mt++) MFMA(afx[mt], bf, acc[mt][cf]);
                }
                bf16x8 bn0 = ld_frag(bb + 4 * 1024);
                bf16x8 bn1 = ld_frag(bb + 5 * 1024);
#pragma unroll
                for (int mt = 0; mt < 2; mt++) {
                    f32x4 z4 = {0.f, 0.f, 0.f, 0.f};
                    tn0[mt] = __builtin_amdgcn_mfma_f32_16x16x32_bf16(afx[mt], bn0, z4, 0, 0, 0);
                    tn1[mt] = __builtin_amdgcn_mfma_f32_16x16x32_bf16(afx[mt], bn1, z4, 0, 0, 0);
                }
            }

            // ---- 16 h-stages ----
            if (hasA) {
#pragma unroll
                for (int s = 0; s < 8; s++) {
                    const unsigned char* bb = smem + (size_t)s * 6144 + lane * 16;
#pragma unroll
                    for (int cf = 0; cf < 6; cf++) {
                        bf16x8 bf = ld_frag(bb + cf * 1024);
#pragma unroll
                        for (int mt = 0; mt < 2; mt++) MFMA(rA[s][mt].v, bf, acc[mt][cf]);
                    }
                }
            }
            if (hasL) {
#pragma unroll
                for (int s = 0; s < 8; s++) {
                    const unsigned char* bb = smem + (size_t)(8 + s) * 6144 + lane * 16;
#pragma unroll
                    for (int cf = 0; cf < 6; cf++) {
                        bf16x8 bf = ld_frag(bb + cf * 1024);
#pragma unroll
                        for (int mt = 0; mt < 2; mt++) MFMA(rL[s][mt].v, bf, acc[mt][cf]);
                    }
                }
            }

            // ---- back-pressure before overwriting slot (j, i%D) ----
            if (j < Nx - 1 && i >= D)
                wait_ge(cons + (size_t)j * fstride, 8u * (unsigned)(i - (D - 1)));

            // ---- epilogue: gates, state update, coalesced sc0sc1 stores ----
            char* sO = hbg + ((size_t)j * D + slot) * 16384;
#pragma unroll
            for (int mt = 0; mt < 2; mt++) {
#pragma unroll
                for (int e = 0; e < 4; e++) {
                    int m = mt * 16 + q * 4 + e;
                    float rv0 = sigf(acc[mt][0][e] + bR0);
                    float zv0 = sigf(acc[mt][2][e] + bZ0);
                    float nv0 = tanhf_fast(tn0[mt][e] + bN0 + rv0 * acc[mt][4][e]);
                    float rv1 = sigf(acc[mt][1][e] + bR1);
                    float zv1 = sigf(acc[mt][3][e] + bZ1);
                    float nv1 = tanhf_fast(tn1[mt][e] + bN1 + rv1 * acc[mt][5][e]);
                    float hs0 = 0.f, hs1 = 0.f;
                    if (hasA) {
                        unsigned v = hsA[mt * 4 + e];
                        hs0 += bf16_lo(v); hs1 += bf16_hi(v);
                    }
                    if (hasL) {
                        unsigned v = hsL[mt * 4 + e];
                        hs0 += bf16_lo(v); hs1 += bf16_hi(v);
                    }
                    float h0 = (1.f - zv0) * nv0 + 0.5f * zv0 * hs0;
                    float h1 = (1.f - zv1) * nv1 + 0.5f * zv1 * hs1;
                    st4_sc01(sO + (size_t)g * 2048 + (size_t)m * 64 + l16 * 4,
                             bf16_bits(h0) | (bf16_bits(h1) << 16));
                }
            }

            wait_vm0();   // h stores at the L3 coherence point
            if (lane == 0) {
                __hip_atomic_fetch_add(prog + (size_t)j * fstride, 1u, __ATOMIC_RELAXED,
                                       __HIP_MEMORY_SCOPE_AGENT);
                if (hasL)
                    __hip_atomic_fetch_add(cons + (size_t)(j - 1) * fstride, 1u,
                                           __ATOMIC_RELAXED, __HIP_MEMORY_SCOPE_AGENT);
            }
        }
    }
}

// ---------------------------------------------------------------------------
// Output: logits = hcat @ W_out + b_out, then log_softmax. One wave per batch.
// ---------------------------------------------------------------------------
__global__ __launch_bounds__(64) void out_kernel(const char* __restrict__ hbuf,
    const float* __restrict__ Wout, const float* __restrict__ bout,
    float* __restrict__ out, int D)
{
    int b = blockIdx.x;
    int tt = threadIdx.x;
    size_t gslice = (size_t)29 * D * 16384;
    float accv[10];
#pragma unroll
    for (int o = 0; o < 10; o++) accv[o] = 0.f;
    for (int it = 0; it < 16; ++it) {
        int k = it * 64 + tt;
        int a = k >> 8, c = k & 255;
        int Ny = 29 - (a & 1), Nx = 29 - ((a >> 1) & 1);
        int G  = a * 8 + (b >> 5);
        int c31 = c & 31;
        int pos = ((c31 & 15) << 1) | (c31 >> 4);
        const __bf16* hp = (const __bf16*)(hbuf + (size_t)G * gslice
                           + ((size_t)(Nx - 1) * D + (Ny - 1) % D) * 16384
                           + (size_t)(c >> 5) * 2048 + (size_t)(b & 31) * 64
                           + (size_t)pos * 2);
        float h = (float)(*hp);
        const float* wr = Wout + k * 10;
#pragma unroll
        for (int o = 0; o < 10; o++) accv[o] += h * wr[o];
    }
#pragma unroll
    for (int off = 32; off > 0; off >>= 1)
#pragma unroll
        for (int o = 0; o < 10; o++) accv[o] += __shfl_down(accv[o], off, 64);
    if (tt == 0) {
        float l[10];
#pragma unroll
        for (int o = 0; o < 10; o++) l[o] = accv[o] + bout[o];
        float mx = l[0];
#pragma unroll
        for (int o = 1; o < 10; o++) mx = fmaxf(mx, l[o]);
        float se = 0.f;
#pragma unroll
        for (int o = 0; o < 10; o++) se += __expf(l[o] - mx);
        float lse = mx + __logf(se);
#pragma unroll
        for (int o = 0; o < 10; o++) out[b * 10 + o] = l[o] - lse;
    }
}

extern "C" void kernel_launch(void* const* d_in, const int* in_sizes, int n_in,
                              void* d_out, int out_size, void* d_ws, size_t ws_size,
                              hipStream_t stream) {
    const float* x    = (const float*)d_in[0];
    const float* Wx   = (const float*)d_in[1];
    const float* Uh   = (const float*)d_in[2];
    const float* Uh2  = (const float*)d_in[3];
    const float* b    = (const float*)d_in[4];
    const float* Wout = (const float*)d_in[5];
    const float* bout = (const float*)d_in[6];
    float* out = (float*)d_out;

    char* ws = (char*)d_ws;
    const size_t PACK_PAD  = 3407872;
    const size_t XPACK_END = 31457280;       // pack + xpack (padded)
    const size_t FLAGS_PAD = 131072;         // 2048 counters x 64B (fstride 16)
    const size_t FLAGS_R12 = 8192;           // fstride 1 (exact R12)
    auto hbytes = [](int d) { return (size_t)32 * 29 * d * 16384; };

    // tiered layout: deepest ring that fits; degrade gracefully.
    bool use_xp; size_t hbuf_off; int D; int fstride; size_t flag_bytes;
    if (ws_size >= XPACK_END + hbytes(12) + FLAGS_PAD) {
        use_xp = true;  hbuf_off = XPACK_END; D = 12; fstride = 16; flag_bytes = FLAGS_PAD;
    } else if (ws_size >= XPACK_END + hbytes(8) + FLAGS_PAD) {
        use_xp = true;  hbuf_off = XPACK_END; D = 8;  fstride = 16; flag_bytes = FLAGS_PAD;
    } else if (ws_size >= XPACK_END + hbytes(6) + FLAGS_PAD) {
        use_xp = true;  hbuf_off = XPACK_END; D = 6;  fstride = 16; flag_bytes = FLAGS_PAD;
    } else if (ws_size >= XPACK_END + hbytes(3) + FLAGS_PAD) {
        use_xp = true;  hbuf_off = XPACK_END; D = 3;  fstride = 16; flag_bytes = FLAGS_PAD;
    } else if (ws_size >= XPACK_END + hbytes(3) + FLAGS_R12) {
        use_xp = true;  hbuf_off = XPACK_END; D = 3;  fstride = 1;  flag_bytes = FLAGS_R12;
    } else {
        use_xp = false; hbuf_off = PACK_PAD;  D = 3;  fstride = 1;  flag_bytes = FLAGS_R12;
    }

    uint4*  packW = (uint4*)ws;
    uint4*  xpack = use_xp ? (uint4*)(ws + PACK_PAD) : nullptr;
    char*   hbuf  = ws + hbuf_off;
    unsigned* flags = (unsigned*)(ws + hbuf_off + hbytes(D));

    (void)hipFuncSetAttribute((const void*)persist_kernel,
                              hipFuncAttributeMaxDynamicSharedMemorySize, 104448);

    hipMemsetAsync(flags, 0, flag_bytes, stream);
    pack_kernel<<<816, 256, 0, stream>>>(Wx, Uh, Uh2, packW);
    if (use_xp)
        xpack_kernel<<<6728, 256, 0, stream>>>(x, xpack);

    void* args[] = { (void*)&x, (void*)&xpack, (void*)&packW, (void*)&b,
                     (void*)&hbuf, (void*)&flags, (void*)&D, (void*)&fstride };
    hipLaunchCooperativeKernel((void*)persist_kernel, dim3(256), dim3(512),
                               args, 104448, stream);

    out_kernel<<<256, 64, 0, stream>>>(hbuf, Wout, bout, out, D);
}